// Round 9
// baseline (400.021 us; speedup 1.0000x reference)
//
#include <hip/hip_runtime.h>
#include <hip/hip_bf16.h>

typedef __bf16 bf16;
typedef __attribute__((ext_vector_type(8))) __bf16 bf16x8;
typedef __attribute__((ext_vector_type(4))) float floatx4;

#define B_  4
#define C_  512
#define H_  96
#define W_  96
#define HD_ 64
#define HW_ 9216
#define BH_ 32
#define SCALING_ 0.125f
#define BHS_ 589824          // 96*96*64 elems per bh in d-inner layout

static constexpr size_t T_ELEMS = (size_t)BH_ * HD_ * HW_;   // 18,874,368
static constexpr size_t S_ELEMS = (size_t)BH_ * HW_;         // 294,912

// ---------------------------------------------------------------------------
// Kernel 0a: cast weights fp32 -> bf16, concatenated Wb[3][512][512]
// ---------------------------------------------------------------------------
__global__ __launch_bounds__(256) void cast_w(
    const float* __restrict__ Wq, const float* __restrict__ Wk, const float* __restrict__ Wv,
    bf16* __restrict__ Wb)
{
    const int i  = blockIdx.x * 256 + threadIdx.x;   // < 196608
    const int e0 = i * 4;
    const int arr = e0 >> 18;
    const int off = e0 & 262143;
    const float* W = (arr == 0) ? Wq : (arr == 1) ? Wk : Wv;
    const float4 val = *(const float4*)(W + off);
    bf16 tmp[4] __attribute__((aligned(8)));
    tmp[0] = (bf16)val.x; tmp[1] = (bf16)val.y; tmp[2] = (bf16)val.z; tmp[3] = (bf16)val.w;
    *(uint2*)(Wb + e0) = *(const uint2*)tmp;
}

// ---------------------------------------------------------------------------
// Kernel 0b: cast + transpose q,v fp32 [b][c][p] -> bf16 [b][p][c]
// ---------------------------------------------------------------------------
__global__ __launch_bounds__(256) void cast_qv(
    const float* __restrict__ q, const float* __restrict__ v,
    bf16* __restrict__ qbT, bf16* __restrict__ vbT)
{
    const int z = blockIdx.z;
    const int s = z >> 2, b = z & 3;
    const float* sb = (s ? v : q) + (size_t)b * C_ * HW_;
    bf16*       db = (s ? vbT : qbT) + (size_t)b * HW_ * C_;
    const int p0 = blockIdx.x * 64, c0 = blockIdx.y * 64;

    __shared__ float ts[64][65];
    const int tid = threadIdx.x;

    for (int i = tid; i < 1024; i += 256) {
        const int row = i >> 4, seg = i & 15;
        const float4 val = *(const float4*)(sb + (size_t)(c0 + row) * HW_ + p0 + seg * 4);
        ts[row][seg * 4 + 0] = val.x; ts[row][seg * 4 + 1] = val.y;
        ts[row][seg * 4 + 2] = val.z; ts[row][seg * 4 + 3] = val.w;
    }
    __syncthreads();
    for (int i = tid; i < 512; i += 256) {
        const int prow = i >> 3, cseg = i & 7;
        bf16 tmp[8] __attribute__((aligned(16)));
        #pragma unroll
        for (int k = 0; k < 8; k++) tmp[k] = (bf16)ts[cseg * 8 + k][prow];
        *(uint4*)(db + (size_t)(p0 + prow) * C_ + c0 + cseg * 8) = *(const uint4*)tmp;
    }
}

// ---------------------------------------------------------------------------
// conv GEMM helpers (XOR-swizzled LDS chunks; HW-verified rounds 4/5).
// ---------------------------------------------------------------------------
__device__ __forceinline__ void stage_swz(
    const bf16* __restrict__ A, const bf16* __restrict__ Bsrc,
    int o0, int p0, int k0, int tid, bf16* As, bf16* Bs)
{
    #pragma unroll
    for (int c = tid; c < 512; c += 256) {
        const int sc = c ^ ((c >> 3) & 7);          // swizzled logical chunk
        const int row = sc >> 2, seg = sc & 3;
        const bf16* gA = A    + (size_t)(o0 + row) * C_ + k0 + seg * 8;
        const bf16* gB = Bsrc + (size_t)(p0 + row) * C_ + k0 + seg * 8;
#if __has_builtin(__builtin_amdgcn_global_load_lds)
        char* lA = (char*)As + (size_t)(c & ~63) * 16;
        char* lB = (char*)Bs + (size_t)(c & ~63) * 16;
        __builtin_amdgcn_global_load_lds((const __attribute__((address_space(1))) void*)gA,
                                         (__attribute__((address_space(3))) void*)lA, 16, 0, 0);
        __builtin_amdgcn_global_load_lds((const __attribute__((address_space(1))) void*)gB,
                                         (__attribute__((address_space(3))) void*)lB, 16, 0, 0);
#else
        *(uint4*)((char*)As + (size_t)c * 16) = *(const uint4*)gA;
        *(uint4*)((char*)Bs + (size_t)c * 16) = *(const uint4*)gB;
#endif
    }
}

__device__ __forceinline__ int swz_chunk(int r, int quad)
{
    return (r * 4 + quad) ^ ((r >> 1) & 7);
}

__device__ __forceinline__ void compute_swz(
    const bf16* As, const bf16* Bs,
    int mrow, int ncol, int l16, int quad, floatx4 acc[4][4])
{
    bf16x8 af[4], bf_[4];
    #pragma unroll
    for (int i = 0; i < 4; i++)
        af[i] = *(const bf16x8*)&As[swz_chunk(mrow + i * 16 + l16, quad) * 8];
    #pragma unroll
    for (int j = 0; j < 4; j++)
        bf_[j] = *(const bf16x8*)&Bs[swz_chunk(ncol + j * 16 + l16, quad) * 8];
    #pragma unroll
    for (int i = 0; i < 4; i++)
        #pragma unroll
        for (int j = 0; j < 4; j++)
            acc[i][j] = __builtin_amdgcn_mfma_f32_16x16x32_bf16(af[i], bf_[j], acc[i][j], 0, 0, 0);
}

// ---------------------------------------------------------------------------
// Kernel 1: conv GEMM — EXACT round-5/8 version (best measured: 88 us).
// Single dispatch, grid (72, 4, 12 = arr*4+b), block 256, LDS 34816 B.
// ---------------------------------------------------------------------------
__global__ __launch_bounds__(256) void conv_mfma(
    const bf16* __restrict__ Wb,
    const float* __restrict__ bq, const float* __restrict__ bk, const float* __restrict__ bv,
    const bf16* __restrict__ qbT, const bf16* __restrict__ vbT,
    bf16* __restrict__ tR, bf16* __restrict__ fR, bf16* __restrict__ g)
{
    const int z = blockIdx.z, arr = z >> 2, b = z & 3;
    const bf16* A    = Wb + (size_t)arr * C_ * C_;
    const bf16* Bsrc = ((arr == 2) ? vbT : qbT) + (size_t)b * HW_ * C_;
    const float* bias = (arr == 0) ? bq : (arr == 1) ? bk : bv;
    const float scale = (arr == 0) ? SCALING_ : 1.0f;

    const int p0 = blockIdx.x * 128;
    const int o0 = blockIdx.y * 128;

    __shared__ __align__(16) bf16 smem[17408];   // 34816 B: dbuf in loop, tile in epilogue
    bf16* const As0 = smem;            // 128*32
    bf16* const Bs0 = smem + 4096;
    bf16* const As1 = smem + 8192;
    bf16* const Bs1 = smem + 12288;

    const int tid = threadIdx.x, lane = tid & 63;
    const int wave = tid >> 6, l16 = lane & 15, quad = lane >> 4;
    const int mrow = (wave >> 1) * 64, ncol = (wave & 1) * 64;

    floatx4 acc[4][4] = {};

    stage_swz(A, Bsrc, o0, p0, 0, tid, As0, Bs0);
    __syncthreads();

    for (int k0 = 0; k0 < C_; k0 += 64) {
        if (k0 + 32 < C_) stage_swz(A, Bsrc, o0, p0, k0 + 32, tid, As1, Bs1);
        compute_swz(As0, Bs0, mrow, ncol, l16, quad, acc);
        __syncthreads();
        if (k0 + 64 < C_) stage_swz(A, Bsrc, o0, p0, k0 + 64, tid, As0, Bs0);
        compute_swz(As1, Bs1, mrow, ncol, l16, quad, acc);
        __syncthreads();
    }

    if (arr < 2) {
        // swizzled tileT[pl][ol^((pl&7)<<3)], stride 128 (conflict-free)
        #pragma unroll
        for (int i = 0; i < 4; i++)
            #pragma unroll
            for (int r = 0; r < 4; r++) {
                const int ol_ = mrow + i * 16 + quad * 4 + r;
                const float bi = bias[o0 + ol_];
                #pragma unroll
                for (int j = 0; j < 4; j++) {
                    const int pl = ncol + j * 16 + l16;
                    smem[pl * 128 + (ol_ ^ ((pl & 7) << 3))] = (bf16)((acc[i][j][r] + bi) * scale);
                }
            }
        __syncthreads();
        bf16* dst = (arr == 0) ? tR : fR;
        #pragma unroll
        for (int c = tid; c < 2048; c += 256) {
            const int pl = c >> 4, oo = c & 15;
            const int pg = p0 + pl;
            const int y = pg / 96, x = pg - y * 96;
            const int og = o0 + oo * 8;
            const int bh = b * 8 + (og >> 6), d = og & 63;
            const size_t di = (size_t)bh * BHS_ + (size_t)y * 6144 + x * 64 + d;
            *(uint4*)(dst + di) = *(const uint4*)&smem[pl * 128 + ((oo ^ (pl & 7)) * 8)];
        }
    } else {
        // tileN[o_local][p_local], stride 136 (writes lane-contiguous)
        const int TS = 136;
        #pragma unroll
        for (int i = 0; i < 4; i++)
            #pragma unroll
            for (int r = 0; r < 4; r++) {
                const int ol_ = mrow + i * 16 + quad * 4 + r;
                const float bi = bias[o0 + ol_];
                #pragma unroll
                for (int j = 0; j < 4; j++) {
                    const int pl = ncol + j * 16 + l16;
                    smem[ol_ * TS + pl] = (bf16)(acc[i][j][r] + bi);
                }
            }
        __syncthreads();
        #pragma unroll
        for (int c = tid; c < 2048; c += 256) {
            const int ol_ = c >> 4, po = c & 15;
            const size_t di = (size_t)(b * 512 + o0 + ol_) * HW_ + p0 + po * 8;
            *(uint4*)(g + di) = *(const uint4*)&smem[ol_ * TS + po * 8];
        }
    }
}

// ---------------------------------------------------------------------------
// Kernel 2: plane transpose g -> gT, vectorized (uint2 = 4 bf16 per access).
// grid (3 strips, 2048 planes), block 256.
// ---------------------------------------------------------------------------
__global__ __launch_bounds__(256) void transpose_g(const bf16* __restrict__ src, bf16* __restrict__ dst)
{
    const int plane = blockIdx.y;
    const int y0 = blockIdx.x * 32;
    const bf16* s = src + (size_t)plane * HW_;
    bf16*       d = dst + (size_t)plane * HW_;

    __shared__ bf16 ts[32][100];   // stride 200 B: 8B-aligned, ~4-way col-read conflict
    const int tid = threadIdx.x;

    #pragma unroll
    for (int i = tid; i < 768; i += 256) {
        const int row = i / 24, seg = i % 24;
        *(uint2*)&ts[row][seg * 4] = *(const uint2*)(s + (size_t)(y0 + row) * W_ + seg * 4);
    }
    __syncthreads();
    #pragma unroll
    for (int i = tid; i < 768; i += 256) {
        const int x = i >> 3, yseg = i & 7;
        bf16 tmp[4] __attribute__((aligned(8)));
        #pragma unroll
        for (int k = 0; k < 4; k++) tmp[k] = ts[yseg * 4 + k][x];
        *(uint2*)(d + (size_t)x * H_ + y0 + yseg * 4) = *(const uint2*)tmp;
    }
}

// ---------------------------------------------------------------------------
// Kernel 3: column attention.  Block (x, bh), 512 threads / 8 waves.
// LDS 47616 B (tl+fl+el) -> 3 blocks/CU; gl staged post-QK^T into fl space.
// EXACT round-8 version.
// ---------------------------------------------------------------------------
__global__ __launch_bounds__(512) void attn_col(
    const bf16* __restrict__ tR, const bf16* __restrict__ fR, const bf16* __restrict__ gT,
    bf16* __restrict__ outC, float* __restrict__ mc, float* __restrict__ lc)
{
    const int x = blockIdx.x;
    const int bh = blockIdx.y;

    __shared__ __align__(16) bf16 tl[96][72];
    __shared__ __align__(16) bf16 fl[96][72];
    __shared__ __align__(16) bf16 el[96][104];
    // total 47616 B -> 3 blocks/CU

    const int tid = threadIdx.x;
    const size_t sbase = (size_t)bh * BHS_;

    for (int i = tid; i < 768; i += 512) {
        const int y = i >> 3, oct = i & 7;
        const size_t gi = sbase + (size_t)y * 6144 + (size_t)x * 64 + oct * 8;
        *(uint4*)&tl[y][oct * 8] = *(const uint4*)(tR + gi);
        *(uint4*)&fl[y][oct * 8] = *(const uint4*)(fR + gi);
    }
    __syncthreads();

    const int lane = tid & 63, wave = tid >> 6;
    const int l16 = lane & 15, quad = lane >> 4;

    // QK^T: 36 16x16 tiles over 8 waves
    __builtin_amdgcn_s_setprio(1);
    #pragma unroll
    for (int it = 0; it < 5; it++) {
        const int idx = wave + it * 8;
        if (idx < 36) {
            const int mt = idx / 6, nt = idx % 6;
            floatx4 a = {};
            #pragma unroll
            for (int ks = 0; ks < 2; ks++) {
                bf16x8 af = *(const bf16x8*)&tl[mt * 16 + l16][ks * 32 + quad * 8];
                bf16x8 bf_ = *(const bf16x8*)&fl[nt * 16 + l16][ks * 32 + quad * 8];
                a = __builtin_amdgcn_mfma_f32_16x16x32_bf16(af, bf_, a, 0, 0, 0);
            }
            #pragma unroll
            for (int r = 0; r < 4; r++) {
                const int row = mt * 16 + quad * 4 + r, col = nt * 16 + l16;
                el[row][col] = (row == col) ? (bf16)(-1e30f) : (bf16)a[r];
            }
        }
    }
    __builtin_amdgcn_s_setprio(0);
    __syncthreads();

    // gl staging into fl overlay (fl dead after QK^T) — overlaps softmax
    bf16 (*gl)[104] = (bf16 (*)[104])fl;   // 64*104 = 6656 <= 6912 elems
    const size_t gbase = sbase + (size_t)x * 96;   // gT[bh][d][x][*y]
    for (int i = tid; i < 768; i += 512) {
        const int d = i / 12, seg = i % 12;
        *(uint4*)&gl[d][seg * 8] = *(const uint4*)(gT + gbase + (size_t)d * HW_ + seg * 8);
    }

    // softmax: 4 threads per row, 24 vals each
    if (tid < 384) {
        const int r = tid >> 2, qu = tid & 3;
        float vals[24];
        float m = -1e30f;
        #pragma unroll
        for (int k = 0; k < 3; k++) {
            bf16x8 v8 = *(const bf16x8*)&el[r][qu * 24 + k * 8];
            #pragma unroll
            for (int e = 0; e < 8; e++) { vals[k * 8 + e] = (float)v8[e]; m = fmaxf(m, vals[k * 8 + e]); }
        }
        m = fmaxf(m, __shfl_xor(m, 1));
        m = fmaxf(m, __shfl_xor(m, 2));
        float s = 0.f;
        #pragma unroll
        for (int k = 0; k < 3; k++) {
            bf16 tmp[8] __attribute__((aligned(16)));
            #pragma unroll
            for (int e = 0; e < 8; e++) {
                const float p = __expf(vals[k * 8 + e] - m);
                s += p; tmp[e] = (bf16)p;
            }
            *(uint4*)&el[r][qu * 24 + k * 8] = *(const uint4*)tmp;
        }
        s += __shfl_xor(s, 1);
        s += __shfl_xor(s, 2);
        if (qu == 0) {
            mc[(size_t)bh * HW_ + x * 96 + r] = m;
            lc[(size_t)bh * HW_ + x * 96 + r] = s;
        }
    }
    __syncthreads();

    // PV: 24 16x16 tiles over 8 waves, out[j=y][d] into ol (overlays tl)
    bf16 (*ol)[72] = tl;
    __builtin_amdgcn_s_setprio(1);
    #pragma unroll
    for (int it = 0; it < 3; it++) {
        const int idx = wave + it * 8;
        const int mt = idx >> 2, nt = idx & 3;
        floatx4 a = {};
        #pragma unroll
        for (int ks = 0; ks < 3; ks++) {
            bf16x8 pf = *(const bf16x8*)&el[mt * 16 + l16][ks * 32 + quad * 8];
            bf16x8 gf = *(const bf16x8*)&gl[nt * 16 + l16][ks * 32 + quad * 8];
            a = __builtin_amdgcn_mfma_f32_16x16x32_bf16(pf, gf, a, 0, 0, 0);
        }
        #pragma unroll
        for (int r = 0; r < 4; r++)
            ol[mt * 16 + quad * 4 + r][nt * 16 + l16] = (bf16)a[r];
    }
    __builtin_amdgcn_s_setprio(0);
    __syncthreads();

    bf16* ob = outC + sbase + (size_t)x * 6144;
    for (int i = tid; i < 768; i += 512) {
        const int j = i >> 3, oct = i & 7;
        *(uint4*)(ob + (size_t)j * 64 + oct * 8) = *(const uint4*)&ol[j][oct * 8];
    }
}

// ---------------------------------------------------------------------------
// Kernel 4: row attention + fused merge.  Block (y, bh), 512 threads.
// LDS shrunk to 49152 B (tl+fl+el+stats) -> 3 blocks/CU, 24 waves:
//   gl staged post-QK^T into tl footprint; ocl into fl; PV accumulates in
//   registers, results written to el footprint after a barrier; merge reads
//   from there.  T14 early-issue + T5 setprio retained.
// ---------------------------------------------------------------------------
__global__ __launch_bounds__(512) void attn_row_merge(
    const bf16* __restrict__ tR, const bf16* __restrict__ fR, const bf16* __restrict__ g,
    const bf16* __restrict__ outC, const float* __restrict__ mc, const float* __restrict__ lc,
    const float* __restrict__ v, const float* __restrict__ gamma, float* __restrict__ out)
{
    const int y = blockIdx.x;
    const int bh = blockIdx.y;

    __shared__ __align__(16) bf16 tl[96][72];
    __shared__ __align__(16) bf16 fl[96][72];
    __shared__ __align__(16) bf16 el[96][104];
    __shared__ float mll[96], lll[96], wrl[96], wcl[96];
    // total 49152 B -> 3 blocks/CU

    const int tid = threadIdx.x;
    const size_t sbase = (size_t)bh * BHS_;
    const size_t slice = sbase + (size_t)y * 6144;

    for (int i = tid; i < 768; i += 512) {
        const int j = i >> 3, oct = i & 7;
        *(uint4*)&tl[j][oct * 8] = *(const uint4*)(tR + slice + (size_t)j * 64 + oct * 8);
        *(uint4*)&fl[j][oct * 8] = *(const uint4*)(fR + slice + (size_t)j * 64 + oct * 8);
    }

    // --- T14 early-issue (static 2-step unroll, rule #20) ------------------
    uint4 oc0, oc1 = {};
    {
        const int xx = tid >> 3, oct = tid & 7;            // items 0..511
        oc0 = *(const uint4*)(outC + sbase + (size_t)xx * 6144 + (size_t)y * 64 + oct * 8);
    }
    if (tid < 256) {
        const int i1 = tid + 512, xx = i1 >> 3, oct = i1 & 7;   // items 512..767
        oc1 = *(const uint4*)(outC + sbase + (size_t)xx * 6144 + (size_t)y * 64 + oct * 8);
    }
    float4 vp0a, vp0b, vp1a = {}, vp1b = {};
    {
        const int xo = tid >> 6, d = tid & 63;             // items 0..511
        const size_t ob = sbase + (size_t)d * HW_ + (size_t)y * 96 + xo * 8;
        vp0a = *(const float4*)(v + ob);
        vp0b = *(const float4*)(v + ob + 4);
    }
    if (tid < 256) {
        const int i1 = tid + 512, xo = i1 >> 6, d = i1 & 63;    // items 512..767
        const size_t ob = sbase + (size_t)d * HW_ + (size_t)y * 96 + xo * 8;
        vp1a = *(const float4*)(v + ob);
        vp1b = *(const float4*)(v + ob + 4);
    }
    float mcv = 0.f, lcv = 0.f;
    if (tid < 96) {
        mcv = mc[(size_t)bh * HW_ + tid * 96 + y];
        lcv = lc[(size_t)bh * HW_ + tid * 96 + y];
    }
    __syncthreads();

    const int lane = tid & 63, wave = tid >> 6;
    const int l16 = lane & 15, quad = lane >> 4;

    // QK^T: 36 tiles over 8 waves
    __builtin_amdgcn_s_setprio(1);
    #pragma unroll
    for (int it = 0; it < 5; it++) {
        const int idx = wave + it * 8;
        if (idx < 36) {
            const int mt = idx / 6, nt = idx % 6;
            floatx4 a = {};
            #pragma unroll
            for (int ks = 0; ks < 2; ks++) {
                bf16x8 af = *(const bf16x8*)&tl[mt * 16 + l16][ks * 32 + quad * 8];
                bf16x8 bf_ = *(const bf16x8*)&fl[nt * 16 + l16][ks * 32 + quad * 8];
                a = __builtin_amdgcn_mfma_f32_16x16x32_bf16(af, bf_, a, 0, 0, 0);
            }
            #pragma unroll
            for (int r = 0; r < 4; r++)
                el[mt * 16 + quad * 4 + r][nt * 16 + l16] = (bf16)a[r];
        }
    }
    __builtin_amdgcn_s_setprio(0);
    __syncthreads();

    // gl staging into tl overlay (tl dead after QK^T) — overlaps softmax
    bf16 (*gl)[104] = (bf16 (*)[104])tl;   // 64*104 = 6656 <= 6912 elems
    const size_t gbase = sbase + (size_t)y * 96;   // g[bh][d][y][*x]
    for (int i = tid; i < 768; i += 512) {
        const int d = i / 12, seg = i % 12;
        *(uint4*)&gl[d][seg * 8] = *(const uint4*)(g + gbase + (size_t)d * HW_ + seg * 8);
    }

    // ocl write (overlay fl; fl dead after QK^T barrier)
    bf16 (*ocl)[72] = fl;
    {
        const int xx = tid >> 3, oct = tid & 7;
        *(uint4*)&ocl[xx][oct * 8] = oc0;
    }
    if (tid < 256) {
        const int i1 = tid + 512, xx = i1 >> 3, oct = i1 & 7;
        *(uint4*)&ocl[xx][oct * 8] = oc1;
    }

    // softmax: 4 threads per row
    if (tid < 384) {
        const int r = tid >> 2, qu = tid & 3;
        float vals[24];
        float m = -1e30f;
        #pragma unroll
        for (int k = 0; k < 3; k++) {
            bf16x8 v8 = *(const bf16x8*)&el[r][qu * 24 + k * 8];
            #pragma unroll
            for (int e = 0; e < 8; e++) { vals[k * 8 + e] = (float)v8[e]; m = fmaxf(m, vals[k * 8 + e]); }
        }
        m = fmaxf(m, __shfl_xor(m, 1));
        m = fmaxf(m, __shfl_xor(m, 2));
        float s = 0.f;
        #pragma unroll
        for (int k = 0; k < 3; k++) {
            bf16 tmp[8] __attribute__((aligned(16)));
            #pragma unroll
            for (int e = 0; e < 8; e++) {
                const float p = __expf(vals[k * 8 + e] - m);
                s += p; tmp[e] = (bf16)p;
            }
            *(uint4*)&el[r][qu * 24 + k * 8] = *(const uint4*)tmp;
        }
        s += __shfl_xor(s, 1);
        s += __shfl_xor(s, 2);
        if (qu == 0) { mll[r] = m; lll[r] = s; }
    }
    __syncthreads();

    // merged-weight computation (uses prefetched mcv/lcv) + PV in registers
    if (tid < 96) {
        const float mrv = mll[tid], lrv = lll[tid];
        const float mm = fmaxf(mrv, mcv);
        const float wr = __expf(mrv - mm), wc = __expf(mcv - mm);
        const float dn = lrv * wr + lcv * wc;
        wrl[tid] = wr / dn;
        wcl[tid] = wc / dn;
    }
    floatx4 pa[3] = {};
    __builtin_amdgcn_s_setprio(1);
    #pragma unroll
    for (int it = 0; it < 3; it++) {
        const int idx = wave + it * 8;
        const int mt = idx >> 2, nt = idx & 3;
        #pragma unroll
        for (int ks = 0; ks < 3; ks++) {
            bf16x8 pf = *(const bf16x8*)&el[mt * 16 + l16][ks * 32 + quad * 8];
            bf16x8 gf = *(const bf16x8*)&gl[nt * 16 + l16][ks * 32 + quad * 8];
            pa[it] = __builtin_amdgcn_mfma_f32_16x16x32_bf16(pf, gf, pa[it], 0, 0, 0);
        }
    }
    __builtin_amdgcn_s_setprio(0);
    __syncthreads();   // all PV reads of el/gl complete

    // write PV results into el footprint (stride 104)
    #pragma unroll
    for (int it = 0; it < 3; it++) {
        const int idx = wave + it * 8;
        const int mt = idx >> 2, nt = idx & 3;
        #pragma unroll
        for (int r = 0; r < 4; r++)
            el[mt * 16 + quad * 4 + r][nt * 16 + l16] = (bf16)pa[it][r];
    }
    __syncthreads();

    // merge + final output from prefetched v registers (ol = el overlay)
    const float gam = gamma[0];
    {
        const int xo = tid >> 6, d = tid & 63;
        const int x0 = xo * 8;
        float res[8];
        #pragma unroll
        for (int k = 0; k < 8; k++) {
            const int xx = x0 + k;
            res[k] = (float)el[xx][d] * wrl[xx] + (float)ocl[xx][d] * wcl[xx];
        }
        const size_t ob = sbase + (size_t)d * HW_ + (size_t)y * 96 + x0;
        float4 r0, r1;
        r0.x = gam * res[0] + vp0a.x; r0.y = gam * res[1] + vp0a.y;
        r0.z = gam * res[2] + vp0a.z; r0.w = gam * res[3] + vp0a.w;
        r1.x = gam * res[4] + vp0b.x; r1.y = gam * res[5] + vp0b.y;
        r1.z = gam * res[6] + vp0b.z; r1.w = gam * res[7] + vp0b.w;
        *(float4*)(out + ob) = r0;
        *(float4*)(out + ob + 4) = r1;
    }
    if (tid < 256) {
        const int i1 = tid + 512;
        const int xo = i1 >> 6, d = i1 & 63;
        const int x0 = xo * 8;
        float res[8];
        #pragma unroll
        for (int k = 0; k < 8; k++) {
            const int xx = x0 + k;
            res[k] = (float)el[xx][d] * wrl[xx] + (float)ocl[xx][d] * wcl[xx];
        }
        const size_t ob = sbase + (size_t)d * HW_ + (size_t)y * 96 + x0;
        float4 r0, r1;
        r0.x = gam * res[0] + vp1a.x; r0.y = gam * res[1] + vp1a.y;
        r0.z = gam * res[2] + vp1a.z; r0.w = gam * res[3] + vp1a.w;
        r1.x = gam * res[4] + vp1b.x; r1.y = gam * res[5] + vp1b.y;
        r1.z = gam * res[6] + vp1b.z; r1.w = gam * res[7] + vp1b.w;
        *(float4*)(out + ob) = r0;
        *(float4*)(out + ob + 4) = r1;
    }
}

// ---------------------------------------------------------------------------
extern "C" void kernel_launch(void* const* d_in, const int* in_sizes, int n_in,
                              void* d_out, int out_size, void* d_ws, size_t ws_size,
                              hipStream_t stream)
{
    const float* q     = (const float*)d_in[0];
    const float* v     = (const float*)d_in[1];
    const float* Wq    = (const float*)d_in[2];
    const float* bq    = (const float*)d_in[3];
    const float* Wk    = (const float*)d_in[4];
    const float* bk    = (const float*)d_in[5];
    const float* Wv    = (const float*)d_in[6];
    const float* bv    = (const float*)d_in[7];
    const float* gamma = (const float*)d_in[8];
    float* out = (float*)d_out;

    char* w = (char*)d_ws;
    const size_t Tb = T_ELEMS * sizeof(bf16);   // 37,748,736 B per slot
    bf16* qbT  = (bf16*)(w + 0 * Tb);   // dead after conv -> reused by outC
    bf16* vbT  = (bf16*)(w + 1 * Tb);   // dead after conv -> reused by gT
    bf16* tR   = (bf16*)(w + 2 * Tb);
    bf16* fR   = (bf16*)(w + 3 * Tb);
    bf16* g    = (bf16*)(w + 4 * Tb);
    bf16* gT   = (bf16*)(w + 1 * Tb);
    bf16* outC = (bf16*)(w + 0 * Tb);
    bf16* Wb   = (bf16*)(w + 6 * Tb);                       // 1.57 MB
    float* mc  = (float*)(w + 6 * Tb + 1572864);
    float* lc  = mc + S_ELEMS;
    // high-water: 6*Tb + 1.57 MB + 2.36 MB = 230.4 MB

    cast_w  <<<dim3(768), 256, 0, stream>>>(Wq, Wk, Wv, Wb);
    cast_qv <<<dim3(144, 8, 8), 256, 0, stream>>>(q, v, qbT, vbT);
    conv_mfma<<<dim3(72, 4, 12), 256, 0, stream>>>(Wb, bq, bk, bv, qbT, vbT, tR, fR, g);
    transpose_g<<<dim3(3, 2048), 256, 0, stream>>>(g, gT);
    attn_col<<<dim3(96, BH_), 512, 0, stream>>>(tR, fR, gT, outC, mc, lc);
    attn_row_merge<<<dim3(96, BH_), 512, 0, stream>>>(tR, fR, g, outC, mc, lc, v, gamma, out);
}

// Round 10
// 390.459 us; speedup vs baseline: 1.0245x; 1.0245x over previous
//
#include <hip/hip_runtime.h>
#include <hip/hip_bf16.h>

typedef __bf16 bf16;
typedef __attribute__((ext_vector_type(8))) __bf16 bf16x8;
typedef __attribute__((ext_vector_type(4))) float floatx4;

#define B_  4
#define C_  512
#define H_  96
#define W_  96
#define HD_ 64
#define HW_ 9216
#define BH_ 32
#define SCALING_ 0.125f
#define BHS_ 589824          // 96*96*64 elems per bh in d-inner layout

static constexpr size_t T_ELEMS = (size_t)BH_ * HD_ * HW_;   // 18,874,368
static constexpr size_t S_ELEMS = (size_t)BH_ * HW_;         // 294,912

// ---------------------------------------------------------------------------
// Kernel 0: cast + transpose q,v fp32 [b][c][p] -> bf16 [b][p][c]
// z==8 slice additionally casts the weights (merged cast_w: one fewer launch).
// ---------------------------------------------------------------------------
__global__ __launch_bounds__(256) void cast_qv(
    const float* __restrict__ q, const float* __restrict__ v,
    const float* __restrict__ Wq, const float* __restrict__ Wk, const float* __restrict__ Wv,
    bf16* __restrict__ qbT, bf16* __restrict__ vbT, bf16* __restrict__ Wb)
{
    const int z = blockIdx.z;
    const int tid = threadIdx.x;

    if (z == 8) {
        // weight cast: 768 logical blocks over the 1152-block slice
        const int bi = blockIdx.y * 144 + blockIdx.x;
        if (bi < 768) {
            const int i  = bi * 256 + tid;       // < 196608
            const int e0 = i * 4;
            const int arr = e0 >> 18;
            const int off = e0 & 262143;
            const float* W = (arr == 0) ? Wq : (arr == 1) ? Wk : Wv;
            const float4 val = *(const float4*)(W + off);
            bf16 tmp[4] __attribute__((aligned(8)));
            tmp[0] = (bf16)val.x; tmp[1] = (bf16)val.y;
            tmp[2] = (bf16)val.z; tmp[3] = (bf16)val.w;
            *(uint2*)(Wb + e0) = *(const uint2*)tmp;
        }
        return;
    }

    const int s = z >> 2, b = z & 3;
    const float* sb = (s ? v : q) + (size_t)b * C_ * HW_;
    bf16*       db = (s ? vbT : qbT) + (size_t)b * HW_ * C_;
    const int p0 = blockIdx.x * 64, c0 = blockIdx.y * 64;

    __shared__ float ts[64][65];

    for (int i = tid; i < 1024; i += 256) {
        const int row = i >> 4, seg = i & 15;
        const float4 val = *(const float4*)(sb + (size_t)(c0 + row) * HW_ + p0 + seg * 4);
        ts[row][seg * 4 + 0] = val.x; ts[row][seg * 4 + 1] = val.y;
        ts[row][seg * 4 + 2] = val.z; ts[row][seg * 4 + 3] = val.w;
    }
    __syncthreads();
    for (int i = tid; i < 512; i += 256) {
        const int prow = i >> 3, cseg = i & 7;
        bf16 tmp[8] __attribute__((aligned(16)));
        #pragma unroll
        for (int k = 0; k < 8; k++) tmp[k] = (bf16)ts[cseg * 8 + k][prow];
        *(uint4*)(db + (size_t)(p0 + prow) * C_ + c0 + cseg * 8) = *(const uint4*)tmp;
    }
}

// ---------------------------------------------------------------------------
// conv GEMM helpers (XOR-swizzled LDS chunks; HW-verified rounds 4/5).
// ---------------------------------------------------------------------------
__device__ __forceinline__ void stage_swz(
    const bf16* __restrict__ A, const bf16* __restrict__ Bsrc,
    int o0, int p0, int k0, int tid, bf16* As, bf16* Bs)
{
    #pragma unroll
    for (int c = tid; c < 512; c += 256) {
        const int sc = c ^ ((c >> 3) & 7);          // swizzled logical chunk
        const int row = sc >> 2, seg = sc & 3;
        const bf16* gA = A    + (size_t)(o0 + row) * C_ + k0 + seg * 8;
        const bf16* gB = Bsrc + (size_t)(p0 + row) * C_ + k0 + seg * 8;
#if __has_builtin(__builtin_amdgcn_global_load_lds)
        char* lA = (char*)As + (size_t)(c & ~63) * 16;
        char* lB = (char*)Bs + (size_t)(c & ~63) * 16;
        __builtin_amdgcn_global_load_lds((const __attribute__((address_space(1))) void*)gA,
                                         (__attribute__((address_space(3))) void*)lA, 16, 0, 0);
        __builtin_amdgcn_global_load_lds((const __attribute__((address_space(1))) void*)gB,
                                         (__attribute__((address_space(3))) void*)lB, 16, 0, 0);
#else
        *(uint4*)((char*)As + (size_t)c * 16) = *(const uint4*)gA;
        *(uint4*)((char*)Bs + (size_t)c * 16) = *(const uint4*)gB;
#endif
    }
}

__device__ __forceinline__ int swz_chunk(int r, int quad)
{
    return (r * 4 + quad) ^ ((r >> 1) & 7);
}

__device__ __forceinline__ void compute_swz(
    const bf16* As, const bf16* Bs,
    int mrow, int ncol, int l16, int quad, floatx4 acc[4][4])
{
    bf16x8 af[4], bf_[4];
    #pragma unroll
    for (int i = 0; i < 4; i++)
        af[i] = *(const bf16x8*)&As[swz_chunk(mrow + i * 16 + l16, quad) * 8];
    #pragma unroll
    for (int j = 0; j < 4; j++)
        bf_[j] = *(const bf16x8*)&Bs[swz_chunk(ncol + j * 16 + l16, quad) * 8];
    #pragma unroll
    for (int i = 0; i < 4; i++)
        #pragma unroll
        for (int j = 0; j < 4; j++)
            acc[i][j] = __builtin_amdgcn_mfma_f32_16x16x32_bf16(af[i], bf_[j], acc[i][j], 0, 0, 0);
}

// ---------------------------------------------------------------------------
// Kernel 1: conv GEMM with 3-buffer ring + counted vmcnt (T4 pipeline).
// Phase i: vmcnt(4) [S(i) landed] ; s_barrier ; issue S(i+2)->buf((i+2)%3) ;
//          ds_read buf(i%3) ; MFMA.   One barrier per phase, never vmcnt(0)
// until the tail -> each stage gets ~2 phases of latency cover.
// grid (72, 4, 12 = arr*4+b), block 256, LDS 49152 B (epilogue overlays).
// ---------------------------------------------------------------------------
__global__ __launch_bounds__(256) void conv_mfma(
    const bf16* __restrict__ Wb,
    const float* __restrict__ bq, const float* __restrict__ bk, const float* __restrict__ bv,
    const bf16* __restrict__ qbT, const bf16* __restrict__ vbT,
    bf16* __restrict__ tR, bf16* __restrict__ fR, bf16* __restrict__ g)
{
    const int z = blockIdx.z, arr = z >> 2, b = z & 3;
    const bf16* A    = Wb + (size_t)arr * C_ * C_;
    const bf16* Bsrc = ((arr == 2) ? vbT : qbT) + (size_t)b * HW_ * C_;
    const float* bias = (arr == 0) ? bq : (arr == 1) ? bk : bv;
    const float scale = (arr == 0) ? SCALING_ : 1.0f;

    const int p0 = blockIdx.x * 128;
    const int o0 = blockIdx.y * 128;

    __shared__ __align__(16) bf16 smem[24576];   // 49152 B: 3-buffer ring; tile in epilogue

    const int tid = threadIdx.x, lane = tid & 63;
    const int wave = tid >> 6, l16 = lane & 15, quad = lane >> 4;
    const int mrow = (wave >> 1) * 64, ncol = (wave & 1) * 64;

    floatx4 acc[4][4] = {};

    // prologue: S0 -> buf0, S1 -> buf1   (8 loads/wave outstanding)
    stage_swz(A, Bsrc, o0, p0, 0,  tid, smem,        smem + 4096);
    stage_swz(A, Bsrc, o0, p0, 32, tid, smem + 8192, smem + 12288);

    #pragma unroll
    for (int i = 0; i < 16; i++) {
        if (i == 15) asm volatile("s_waitcnt vmcnt(0)" ::: "memory");
        else         asm volatile("s_waitcnt vmcnt(4)" ::: "memory");
        __builtin_amdgcn_sched_barrier(0);
        __builtin_amdgcn_s_barrier();
        __builtin_amdgcn_sched_barrier(0);
        if (i + 2 < 16) {
            bf16* base = smem + ((i + 2) % 3) * 8192;
            stage_swz(A, Bsrc, o0, p0, (i + 2) * 32, tid, base, base + 4096);
        }
        const bf16* cur = smem + (i % 3) * 8192;
        compute_swz(cur, cur + 4096, mrow, ncol, l16, quad, acc);
    }
    __syncthreads();

    if (arr < 2) {
        // swizzled tileT[pl][ol^((pl&7)<<3)], stride 128 (conflict-free)
        #pragma unroll
        for (int i = 0; i < 4; i++)
            #pragma unroll
            for (int r = 0; r < 4; r++) {
                const int ol_ = mrow + i * 16 + quad * 4 + r;
                const float bi = bias[o0 + ol_];
                #pragma unroll
                for (int j = 0; j < 4; j++) {
                    const int pl = ncol + j * 16 + l16;
                    smem[pl * 128 + (ol_ ^ ((pl & 7) << 3))] = (bf16)((acc[i][j][r] + bi) * scale);
                }
            }
        __syncthreads();
        bf16* dst = (arr == 0) ? tR : fR;
        #pragma unroll
        for (int c = tid; c < 2048; c += 256) {
            const int pl = c >> 4, oo = c & 15;
            const int pg = p0 + pl;
            const int y = pg / 96, x = pg - y * 96;
            const int og = o0 + oo * 8;
            const int bh = b * 8 + (og >> 6), d = og & 63;
            const size_t di = (size_t)bh * BHS_ + (size_t)y * 6144 + x * 64 + d;
            *(uint4*)(dst + di) = *(const uint4*)&smem[pl * 128 + ((oo ^ (pl & 7)) * 8)];
        }
    } else {
        // tileN[o_local][p_local], stride 136 (writes lane-contiguous)
        const int TS = 136;
        #pragma unroll
        for (int i = 0; i < 4; i++)
            #pragma unroll
            for (int r = 0; r < 4; r++) {
                const int ol_ = mrow + i * 16 + quad * 4 + r;
                const float bi = bias[o0 + ol_];
                #pragma unroll
                for (int j = 0; j < 4; j++) {
                    const int pl = ncol + j * 16 + l16;
                    smem[ol_ * TS + pl] = (bf16)(acc[i][j][r] + bi);
                }
            }
        __syncthreads();
        #pragma unroll
        for (int c = tid; c < 2048; c += 256) {
            const int ol_ = c >> 4, po = c & 15;
            const size_t di = (size_t)(b * 512 + o0 + ol_) * HW_ + p0 + po * 8;
            *(uint4*)(g + di) = *(const uint4*)&smem[ol_ * TS + po * 8];
        }
    }
}

// ---------------------------------------------------------------------------
// Kernel 2: plane transpose g -> gT, vectorized (uint2 = 4 bf16 per access).
// grid (3 strips, 2048 planes), block 256.
// ---------------------------------------------------------------------------
__global__ __launch_bounds__(256) void transpose_g(const bf16* __restrict__ src, bf16* __restrict__ dst)
{
    const int plane = blockIdx.y;
    const int y0 = blockIdx.x * 32;
    const bf16* s = src + (size_t)plane * HW_;
    bf16*       d = dst + (size_t)plane * HW_;

    __shared__ bf16 ts[32][100];   // stride 200 B: 8B-aligned, ~4-way col-read conflict
    const int tid = threadIdx.x;

    #pragma unroll
    for (int i = tid; i < 768; i += 256) {
        const int row = i / 24, seg = i % 24;
        *(uint2*)&ts[row][seg * 4] = *(const uint2*)(s + (size_t)(y0 + row) * W_ + seg * 4);
    }
    __syncthreads();
    #pragma unroll
    for (int i = tid; i < 768; i += 256) {
        const int x = i >> 3, yseg = i & 7;
        bf16 tmp[4] __attribute__((aligned(8)));
        #pragma unroll
        for (int k = 0; k < 4; k++) tmp[k] = ts[yseg * 4 + k][x];
        *(uint2*)(d + (size_t)x * H_ + y0 + yseg * 4) = *(const uint2*)tmp;
    }
}

// ---------------------------------------------------------------------------
// Kernel 3: column attention.  Block (x, bh), 512 threads / 8 waves.
// LDS 47616 B (tl+fl+el) -> 3 blocks/CU; gl staged post-QK^T into fl space.
// EXACT round-8 version.
// ---------------------------------------------------------------------------
__global__ __launch_bounds__(512) void attn_col(
    const bf16* __restrict__ tR, const bf16* __restrict__ fR, const bf16* __restrict__ gT,
    bf16* __restrict__ outC, float* __restrict__ mc, float* __restrict__ lc)
{
    const int x = blockIdx.x;
    const int bh = blockIdx.y;

    __shared__ __align__(16) bf16 tl[96][72];
    __shared__ __align__(16) bf16 fl[96][72];
    __shared__ __align__(16) bf16 el[96][104];
    // total 47616 B -> 3 blocks/CU

    const int tid = threadIdx.x;
    const size_t sbase = (size_t)bh * BHS_;

    for (int i = tid; i < 768; i += 512) {
        const int y = i >> 3, oct = i & 7;
        const size_t gi = sbase + (size_t)y * 6144 + (size_t)x * 64 + oct * 8;
        *(uint4*)&tl[y][oct * 8] = *(const uint4*)(tR + gi);
        *(uint4*)&fl[y][oct * 8] = *(const uint4*)(fR + gi);
    }
    __syncthreads();

    const int lane = tid & 63, wave = tid >> 6;
    const int l16 = lane & 15, quad = lane >> 4;

    // QK^T: 36 16x16 tiles over 8 waves
    __builtin_amdgcn_s_setprio(1);
    #pragma unroll
    for (int it = 0; it < 5; it++) {
        const int idx = wave + it * 8;
        if (idx < 36) {
            const int mt = idx / 6, nt = idx % 6;
            floatx4 a = {};
            #pragma unroll
            for (int ks = 0; ks < 2; ks++) {
                bf16x8 af = *(const bf16x8*)&tl[mt * 16 + l16][ks * 32 + quad * 8];
                bf16x8 bf_ = *(const bf16x8*)&fl[nt * 16 + l16][ks * 32 + quad * 8];
                a = __builtin_amdgcn_mfma_f32_16x16x32_bf16(af, bf_, a, 0, 0, 0);
            }
            #pragma unroll
            for (int r = 0; r < 4; r++) {
                const int row = mt * 16 + quad * 4 + r, col = nt * 16 + l16;
                el[row][col] = (row == col) ? (bf16)(-1e30f) : (bf16)a[r];
            }
        }
    }
    __builtin_amdgcn_s_setprio(0);
    __syncthreads();

    // gl staging into fl overlay (fl dead after QK^T) — overlaps softmax
    bf16 (*gl)[104] = (bf16 (*)[104])fl;   // 64*104 = 6656 <= 6912 elems
    const size_t gbase = sbase + (size_t)x * 96;   // gT[bh][d][x][*y]
    for (int i = tid; i < 768; i += 512) {
        const int d = i / 12, seg = i % 12;
        *(uint4*)&gl[d][seg * 8] = *(const uint4*)(gT + gbase + (size_t)d * HW_ + seg * 8);
    }

    // softmax: 4 threads per row, 24 vals each
    if (tid < 384) {
        const int r = tid >> 2, qu = tid & 3;
        float vals[24];
        float m = -1e30f;
        #pragma unroll
        for (int k = 0; k < 3; k++) {
            bf16x8 v8 = *(const bf16x8*)&el[r][qu * 24 + k * 8];
            #pragma unroll
            for (int e = 0; e < 8; e++) { vals[k * 8 + e] = (float)v8[e]; m = fmaxf(m, vals[k * 8 + e]); }
        }
        m = fmaxf(m, __shfl_xor(m, 1));
        m = fmaxf(m, __shfl_xor(m, 2));
        float s = 0.f;
        #pragma unroll
        for (int k = 0; k < 3; k++) {
            bf16 tmp[8] __attribute__((aligned(16)));
            #pragma unroll
            for (int e = 0; e < 8; e++) {
                const float p = __expf(vals[k * 8 + e] - m);
                s += p; tmp[e] = (bf16)p;
            }
            *(uint4*)&el[r][qu * 24 + k * 8] = *(const uint4*)tmp;
        }
        s += __shfl_xor(s, 1);
        s += __shfl_xor(s, 2);
        if (qu == 0) {
            mc[(size_t)bh * HW_ + x * 96 + r] = m;
            lc[(size_t)bh * HW_ + x * 96 + r] = s;
        }
    }
    __syncthreads();

    // PV: 24 16x16 tiles over 8 waves, out[j=y][d] into ol (overlays tl)
    bf16 (*ol)[72] = tl;
    __builtin_amdgcn_s_setprio(1);
    #pragma unroll
    for (int it = 0; it < 3; it++) {
        const int idx = wave + it * 8;
        const int mt = idx >> 2, nt = idx & 3;
        floatx4 a = {};
        #pragma unroll
        for (int ks = 0; ks < 3; ks++) {
            bf16x8 pf = *(const bf16x8*)&el[mt * 16 + l16][ks * 32 + quad * 8];
            bf16x8 gf = *(const bf16x8*)&gl[nt * 16 + l16][ks * 32 + quad * 8];
            a = __builtin_amdgcn_mfma_f32_16x16x32_bf16(pf, gf, a, 0, 0, 0);
        }
        #pragma unroll
        for (int r = 0; r < 4; r++)
            ol[mt * 16 + quad * 4 + r][nt * 16 + l16] = (bf16)a[r];
    }
    __builtin_amdgcn_s_setprio(0);
    __syncthreads();

    bf16* ob = outC + sbase + (size_t)x * 6144;
    for (int i = tid; i < 768; i += 512) {
        const int j = i >> 3, oct = i & 7;
        *(uint4*)(ob + (size_t)j * 64 + oct * 8) = *(const uint4*)&ol[j][oct * 8];
    }
}

// ---------------------------------------------------------------------------
// Kernel 4: row attention + fused merge.  Block (y, bh), 512 threads.
// EXACT round-9 version (49152 B LDS, 3 blocks/CU, T14 + setprio).
// ---------------------------------------------------------------------------
__global__ __launch_bounds__(512) void attn_row_merge(
    const bf16* __restrict__ tR, const bf16* __restrict__ fR, const bf16* __restrict__ g,
    const bf16* __restrict__ outC, const float* __restrict__ mc, const float* __restrict__ lc,
    const float* __restrict__ v, const float* __restrict__ gamma, float* __restrict__ out)
{
    const int y = blockIdx.x;
    const int bh = blockIdx.y;

    __shared__ __align__(16) bf16 tl[96][72];
    __shared__ __align__(16) bf16 fl[96][72];
    __shared__ __align__(16) bf16 el[96][104];
    __shared__ float mll[96], lll[96], wrl[96], wcl[96];
    // total 49152 B -> 3 blocks/CU

    const int tid = threadIdx.x;
    const size_t sbase = (size_t)bh * BHS_;
    const size_t slice = sbase + (size_t)y * 6144;

    for (int i = tid; i < 768; i += 512) {
        const int j = i >> 3, oct = i & 7;
        *(uint4*)&tl[j][oct * 8] = *(const uint4*)(tR + slice + (size_t)j * 64 + oct * 8);
        *(uint4*)&fl[j][oct * 8] = *(const uint4*)(fR + slice + (size_t)j * 64 + oct * 8);
    }

    // --- T14 early-issue (static 2-step unroll, rule #20) ------------------
    uint4 oc0, oc1 = {};
    {
        const int xx = tid >> 3, oct = tid & 7;            // items 0..511
        oc0 = *(const uint4*)(outC + sbase + (size_t)xx * 6144 + (size_t)y * 64 + oct * 8);
    }
    if (tid < 256) {
        const int i1 = tid + 512, xx = i1 >> 3, oct = i1 & 7;   // items 512..767
        oc1 = *(const uint4*)(outC + sbase + (size_t)xx * 6144 + (size_t)y * 64 + oct * 8);
    }
    float4 vp0a, vp0b, vp1a = {}, vp1b = {};
    {
        const int xo = tid >> 6, d = tid & 63;             // items 0..511
        const size_t ob = sbase + (size_t)d * HW_ + (size_t)y * 96 + xo * 8;
        vp0a = *(const float4*)(v + ob);
        vp0b = *(const float4*)(v + ob + 4);
    }
    if (tid < 256) {
        const int i1 = tid + 512, xo = i1 >> 6, d = i1 & 63;    // items 512..767
        const size_t ob = sbase + (size_t)d * HW_ + (size_t)y * 96 + xo * 8;
        vp1a = *(const float4*)(v + ob);
        vp1b = *(const float4*)(v + ob + 4);
    }
    float mcv = 0.f, lcv = 0.f;
    if (tid < 96) {
        mcv = mc[(size_t)bh * HW_ + tid * 96 + y];
        lcv = lc[(size_t)bh * HW_ + tid * 96 + y];
    }
    __syncthreads();

    const int lane = tid & 63, wave = tid >> 6;
    const int l16 = lane & 15, quad = lane >> 4;

    // QK^T: 36 tiles over 8 waves
    __builtin_amdgcn_s_setprio(1);
    #pragma unroll
    for (int it = 0; it < 5; it++) {
        const int idx = wave + it * 8;
        if (idx < 36) {
            const int mt = idx / 6, nt = idx % 6;
            floatx4 a = {};
            #pragma unroll
            for (int ks = 0; ks < 2; ks++) {
                bf16x8 af = *(const bf16x8*)&tl[mt * 16 + l16][ks * 32 + quad * 8];
                bf16x8 bf_ = *(const bf16x8*)&fl[nt * 16 + l16][ks * 32 + quad * 8];
                a = __builtin_amdgcn_mfma_f32_16x16x32_bf16(af, bf_, a, 0, 0, 0);
            }
            #pragma unroll
            for (int r = 0; r < 4; r++)
                el[mt * 16 + quad * 4 + r][nt * 16 + l16] = (bf16)a[r];
        }
    }
    __builtin_amdgcn_s_setprio(0);
    __syncthreads();

    // gl staging into tl overlay (tl dead after QK^T) — overlaps softmax
    bf16 (*gl)[104] = (bf16 (*)[104])tl;   // 64*104 = 6656 <= 6912 elems
    const size_t gbase = sbase + (size_t)y * 96;   // g[bh][d][y][*x]
    for (int i = tid; i < 768; i += 512) {
        const int d = i / 12, seg = i % 12;
        *(uint4*)&gl[d][seg * 8] = *(const uint4*)(g + gbase + (size_t)d * HW_ + seg * 8);
    }

    // ocl write (overlay fl; fl dead after QK^T barrier)
    bf16 (*ocl)[72] = fl;
    {
        const int xx = tid >> 3, oct = tid & 7;
        *(uint4*)&ocl[xx][oct * 8] = oc0;
    }
    if (tid < 256) {
        const int i1 = tid + 512, xx = i1 >> 3, oct = i1 & 7;
        *(uint4*)&ocl[xx][oct * 8] = oc1;
    }

    // softmax: 4 threads per row
    if (tid < 384) {
        const int r = tid >> 2, qu = tid & 3;
        float vals[24];
        float m = -1e30f;
        #pragma unroll
        for (int k = 0; k < 3; k++) {
            bf16x8 v8 = *(const bf16x8*)&el[r][qu * 24 + k * 8];
            #pragma unroll
            for (int e = 0; e < 8; e++) { vals[k * 8 + e] = (float)v8[e]; m = fmaxf(m, vals[k * 8 + e]); }
        }
        m = fmaxf(m, __shfl_xor(m, 1));
        m = fmaxf(m, __shfl_xor(m, 2));
        float s = 0.f;
        #pragma unroll
        for (int k = 0; k < 3; k++) {
            bf16 tmp[8] __attribute__((aligned(16)));
            #pragma unroll
            for (int e = 0; e < 8; e++) {
                const float p = __expf(vals[k * 8 + e] - m);
                s += p; tmp[e] = (bf16)p;
            }
            *(uint4*)&el[r][qu * 24 + k * 8] = *(const uint4*)tmp;
        }
        s += __shfl_xor(s, 1);
        s += __shfl_xor(s, 2);
        if (qu == 0) { mll[r] = m; lll[r] = s; }
    }
    __syncthreads();

    // merged-weight computation (uses prefetched mcv/lcv) + PV in registers
    if (tid < 96) {
        const float mrv = mll[tid], lrv = lll[tid];
        const float mm = fmaxf(mrv, mcv);
        const float wr = __expf(mrv - mm), wc = __expf(mcv - mm);
        const float dn = lrv * wr + lcv * wc;
        wrl[tid] = wr / dn;
        wcl[tid] = wc / dn;
    }
    floatx4 pa[3] = {};
    __builtin_amdgcn_s_setprio(1);
    #pragma unroll
    for (int it = 0; it < 3; it++) {
        const int idx = wave + it * 8;
        const int mt = idx >> 2, nt = idx & 3;
        #pragma unroll
        for (int ks = 0; ks < 3; ks++) {
            bf16x8 pf = *(const bf16x8*)&el[mt * 16 + l16][ks * 32 + quad * 8];
            bf16x8 gf = *(const bf16x8*)&gl[nt * 16 + l16][ks * 32 + quad * 8];
            pa[it] = __builtin_amdgcn_mfma_f32_16x16x32_bf16(pf, gf, pa[it], 0, 0, 0);
        }
    }
    __builtin_amdgcn_s_setprio(0);
    __syncthreads();   // all PV reads of el/gl complete

    // write PV results into el footprint (stride 104)
    #pragma unroll
    for (int it = 0; it < 3; it++) {
        const int idx = wave + it * 8;
        const int mt = idx >> 2, nt = idx & 3;
        #pragma unroll
        for (int r = 0; r < 4; r++)
            el[mt * 16 + quad * 4 + r][nt * 16 + l16] = (bf16)pa[it][r];
    }
    __syncthreads();

    // merge + final output from prefetched v registers (ol = el overlay)
    const float gam = gamma[0];
    {
        const int xo = tid >> 6, d = tid & 63;
        const int x0 = xo * 8;
        float res[8];
        #pragma unroll
        for (int k = 0; k < 8; k++) {
            const int xx = x0 + k;
            res[k] = (float)el[xx][d] * wrl[xx] + (float)ocl[xx][d] * wcl[xx];
        }
        const size_t ob = sbase + (size_t)d * HW_ + (size_t)y * 96 + x0;
        float4 r0, r1;
        r0.x = gam * res[0] + vp0a.x; r0.y = gam * res[1] + vp0a.y;
        r0.z = gam * res[2] + vp0a.z; r0.w = gam * res[3] + vp0a.w;
        r1.x = gam * res[4] + vp0b.x; r1.y = gam * res[5] + vp0b.y;
        r1.z = gam * res[6] + vp0b.z; r1.w = gam * res[7] + vp0b.w;
        *(float4*)(out + ob) = r0;
        *(float4*)(out + ob + 4) = r1;
    }
    if (tid < 256) {
        const int i1 = tid + 512;
        const int xo = i1 >> 6, d = i1 & 63;
        const int x0 = xo * 8;
        float res[8];
        #pragma unroll
        for (int k = 0; k < 8; k++) {
            const int xx = x0 + k;
            res[k] = (float)el[xx][d] * wrl[xx] + (float)ocl[xx][d] * wcl[xx];
        }
        const size_t ob = sbase + (size_t)d * HW_ + (size_t)y * 96 + x0;
        float4 r0, r1;
        r0.x = gam * res[0] + vp1a.x; r0.y = gam * res[1] + vp1a.y;
        r0.z = gam * res[2] + vp1a.z; r0.w = gam * res[3] + vp1a.w;
        r1.x = gam * res[4] + vp1b.x; r1.y = gam * res[5] + vp1b.y;
        r1.z = gam * res[6] + vp1b.z; r1.w = gam * res[7] + vp1b.w;
        *(float4*)(out + ob) = r0;
        *(float4*)(out + ob + 4) = r1;
    }
}

// ---------------------------------------------------------------------------
extern "C" void kernel_launch(void* const* d_in, const int* in_sizes, int n_in,
                              void* d_out, int out_size, void* d_ws, size_t ws_size,
                              hipStream_t stream)
{
    const float* q     = (const float*)d_in[0];
    const float* v     = (const float*)d_in[1];
    const float* Wq    = (const float*)d_in[2];
    const float* bq    = (const float*)d_in[3];
    const float* Wk    = (const float*)d_in[4];
    const float* bk    = (const float*)d_in[5];
    const float* Wv    = (const float*)d_in[6];
    const float* bv    = (const float*)d_in[7];
    const float* gamma = (const float*)d_in[8];
    float* out = (float*)d_out;

    char* w = (char*)d_ws;
    const size_t Tb = T_ELEMS * sizeof(bf16);   // 37,748,736 B per slot
    bf16* qbT  = (bf16*)(w + 0 * Tb);   // dead after conv -> reused by outC
    bf16* vbT  = (bf16*)(w + 1 * Tb);   // dead after conv -> reused by gT
    bf16* tR   = (bf16*)(w + 2 * Tb);
    bf16* fR   = (bf16*)(w + 3 * Tb);
    bf16* g    = (bf16*)(w + 4 * Tb);
    bf16* gT   = (bf16*)(w + 1 * Tb);
    bf16* outC = (bf16*)(w + 0 * Tb);
    bf16* Wb   = (bf16*)(w + 6 * Tb);                       // 1.57 MB
    float* mc  = (float*)(w + 6 * Tb + 1572864);
    float* lc  = mc + S_ELEMS;
    // high-water: 6*Tb + 1.57 MB + 2.36 MB = 230.4 MB

    cast_qv <<<dim3(144, 8, 9), 256, 0, stream>>>(q, v, Wq, Wk, Wv, qbT, vbT, Wb);
    conv_mfma<<<dim3(72, 4, 12), 256, 0, stream>>>(Wb, bq, bk, bv, qbT, vbT, tR, fR, g);
    transpose_g<<<dim3(3, 2048), 256, 0, stream>>>(g, gT);
    attn_col<<<dim3(96, BH_), 512, 0, stream>>>(tR, fR, gT, outC, mc, lc);
    attn_row_merge<<<dim3(96, BH_), 512, 0, stream>>>(tR, fR, g, outC, mc, lc, v, gamma, out);
}

// Round 11
// 379.896 us; speedup vs baseline: 1.0530x; 1.0278x over previous
//
#include <hip/hip_runtime.h>
#include <hip/hip_bf16.h>

typedef __bf16 bf16;
typedef __attribute__((ext_vector_type(8))) __bf16 bf16x8;
typedef __attribute__((ext_vector_type(4))) float floatx4;

#define B_  4
#define C_  512
#define H_  96
#define W_  96
#define HD_ 64
#define HW_ 9216
#define BH_ 32
#define SCALING_ 0.125f
#define BHS_ 589824          // 96*96*64 elems per bh in d-inner layout

static constexpr size_t T_ELEMS = (size_t)BH_ * HD_ * HW_;   // 18,874,368
static constexpr size_t S_ELEMS = (size_t)BH_ * HW_;         // 294,912

// ---------------------------------------------------------------------------
// Kernel 0: cast + transpose q,v fp32 [b][c][p] -> bf16 [b][p][c]
// z==8 slice additionally casts the weights (merged cast_w).
// ---------------------------------------------------------------------------
__global__ __launch_bounds__(256) void cast_qv(
    const float* __restrict__ q, const float* __restrict__ v,
    const float* __restrict__ Wq, const float* __restrict__ Wk, const float* __restrict__ Wv,
    bf16* __restrict__ qbT, bf16* __restrict__ vbT, bf16* __restrict__ Wb)
{
    const int z = blockIdx.z;
    const int tid = threadIdx.x;

    if (z == 8) {
        const int bi = blockIdx.y * 144 + blockIdx.x;
        if (bi < 768) {
            const int i  = bi * 256 + tid;       // < 196608
            const int e0 = i * 4;
            const int arr = e0 >> 18;
            const int off = e0 & 262143;
            const float* W = (arr == 0) ? Wq : (arr == 1) ? Wk : Wv;
            const float4 val = *(const float4*)(W + off);
            bf16 tmp[4] __attribute__((aligned(8)));
            tmp[0] = (bf16)val.x; tmp[1] = (bf16)val.y;
            tmp[2] = (bf16)val.z; tmp[3] = (bf16)val.w;
            *(uint2*)(Wb + e0) = *(const uint2*)tmp;
        }
        return;
    }

    const int s = z >> 2, b = z & 3;
    const float* sb = (s ? v : q) + (size_t)b * C_ * HW_;
    bf16*       db = (s ? vbT : qbT) + (size_t)b * HW_ * C_;
    const int p0 = blockIdx.x * 64, c0 = blockIdx.y * 64;

    __shared__ float ts[64][65];

    for (int i = tid; i < 1024; i += 256) {
        const int row = i >> 4, seg = i & 15;
        const float4 val = *(const float4*)(sb + (size_t)(c0 + row) * HW_ + p0 + seg * 4);
        ts[row][seg * 4 + 0] = val.x; ts[row][seg * 4 + 1] = val.y;
        ts[row][seg * 4 + 2] = val.z; ts[row][seg * 4 + 3] = val.w;
    }
    __syncthreads();
    for (int i = tid; i < 512; i += 256) {
        const int prow = i >> 3, cseg = i & 7;
        bf16 tmp[8] __attribute__((aligned(16)));
        #pragma unroll
        for (int k = 0; k < 8; k++) tmp[k] = (bf16)ts[cseg * 8 + k][prow];
        *(uint4*)(db + (size_t)(p0 + prow) * C_ + c0 + cseg * 8) = *(const uint4*)tmp;
    }
}

// ---------------------------------------------------------------------------
// conv GEMM helpers (XOR-swizzled LDS chunks; HW-verified rounds 4/5).
// ---------------------------------------------------------------------------
__device__ __forceinline__ void stage_swz(
    const bf16* __restrict__ A, const bf16* __restrict__ Bsrc,
    int o0, int p0, int k0, int tid, bf16* As, bf16* Bs)
{
    #pragma unroll
    for (int c = tid; c < 512; c += 256) {
        const int sc = c ^ ((c >> 3) & 7);          // swizzled logical chunk
        const int row = sc >> 2, seg = sc & 3;
        const bf16* gA = A    + (size_t)(o0 + row) * C_ + k0 + seg * 8;
        const bf16* gB = Bsrc + (size_t)(p0 + row) * C_ + k0 + seg * 8;
#if __has_builtin(__builtin_amdgcn_global_load_lds)
        char* lA = (char*)As + (size_t)(c & ~63) * 16;
        char* lB = (char*)Bs + (size_t)(c & ~63) * 16;
        __builtin_amdgcn_global_load_lds((const __attribute__((address_space(1))) void*)gA,
                                         (__attribute__((address_space(3))) void*)lA, 16, 0, 0);
        __builtin_amdgcn_global_load_lds((const __attribute__((address_space(1))) void*)gB,
                                         (__attribute__((address_space(3))) void*)lB, 16, 0, 0);
#else
        *(uint4*)((char*)As + (size_t)c * 16) = *(const uint4*)gA;
        *(uint4*)((char*)Bs + (size_t)c * 16) = *(const uint4*)gB;
#endif
    }
}

__device__ __forceinline__ int swz_chunk(int r, int quad)
{
    return (r * 4 + quad) ^ ((r >> 1) & 7);
}

__device__ __forceinline__ void compute_swz(
    const bf16* As, const bf16* Bs,
    int mrow, int ncol, int l16, int quad, floatx4 acc[4][4])
{
    bf16x8 af[4], bf_[4];
    #pragma unroll
    for (int i = 0; i < 4; i++)
        af[i] = *(const bf16x8*)&As[swz_chunk(mrow + i * 16 + l16, quad) * 8];
    #pragma unroll
    for (int j = 0; j < 4; j++)
        bf_[j] = *(const bf16x8*)&Bs[swz_chunk(ncol + j * 16 + l16, quad) * 8];
    #pragma unroll
    for (int i = 0; i < 4; i++)
        #pragma unroll
        for (int j = 0; j < 4; j++)
            acc[i][j] = __builtin_amdgcn_mfma_f32_16x16x32_bf16(af[i], bf_[j], acc[i][j], 0, 0, 0);
}

// ---------------------------------------------------------------------------
// Kernel 1: conv GEMM — EXACT round-8 version (best measured: 87 us).
// Single dispatch, grid (72, 4, 12 = arr*4+b), block 256, LDS 34816 B.
// ---------------------------------------------------------------------------
__global__ __launch_bounds__(256) void conv_mfma(
    const bf16* __restrict__ Wb,
    const float* __restrict__ bq, const float* __restrict__ bk, const float* __restrict__ bv,
    const bf16* __restrict__ qbT, const bf16* __restrict__ vbT,
    bf16* __restrict__ tR, bf16* __restrict__ fR, bf16* __restrict__ g)
{
    const int z = blockIdx.z, arr = z >> 2, b = z & 3;
    const bf16* A    = Wb + (size_t)arr * C_ * C_;
    const bf16* Bsrc = ((arr == 2) ? vbT : qbT) + (size_t)b * HW_ * C_;
    const float* bias = (arr == 0) ? bq : (arr == 1) ? bk : bv;
    const float scale = (arr == 0) ? SCALING_ : 1.0f;

    const int p0 = blockIdx.x * 128;
    const int o0 = blockIdx.y * 128;

    __shared__ __align__(16) bf16 smem[17408];   // 34816 B: dbuf in loop, tile in epilogue
    bf16* const As0 = smem;            // 128*32
    bf16* const Bs0 = smem + 4096;
    bf16* const As1 = smem + 8192;
    bf16* const Bs1 = smem + 12288;

    const int tid = threadIdx.x, lane = tid & 63;
    const int wave = tid >> 6, l16 = lane & 15, quad = lane >> 4;
    const int mrow = (wave >> 1) * 64, ncol = (wave & 1) * 64;

    floatx4 acc[4][4] = {};

    stage_swz(A, Bsrc, o0, p0, 0, tid, As0, Bs0);
    __syncthreads();

    for (int k0 = 0; k0 < C_; k0 += 64) {
        if (k0 + 32 < C_) stage_swz(A, Bsrc, o0, p0, k0 + 32, tid, As1, Bs1);
        compute_swz(As0, Bs0, mrow, ncol, l16, quad, acc);
        __syncthreads();
        if (k0 + 64 < C_) stage_swz(A, Bsrc, o0, p0, k0 + 64, tid, As0, Bs0);
        compute_swz(As1, Bs1, mrow, ncol, l16, quad, acc);
        __syncthreads();
    }

    if (arr < 2) {
        // swizzled tileT[pl][ol^((pl&7)<<3)], stride 128 (conflict-free)
        #pragma unroll
        for (int i = 0; i < 4; i++)
            #pragma unroll
            for (int r = 0; r < 4; r++) {
                const int ol_ = mrow + i * 16 + quad * 4 + r;
                const float bi = bias[o0 + ol_];
                #pragma unroll
                for (int j = 0; j < 4; j++) {
                    const int pl = ncol + j * 16 + l16;
                    smem[pl * 128 + (ol_ ^ ((pl & 7) << 3))] = (bf16)((acc[i][j][r] + bi) * scale);
                }
            }
        __syncthreads();
        bf16* dst = (arr == 0) ? tR : fR;
        #pragma unroll
        for (int c = tid; c < 2048; c += 256) {
            const int pl = c >> 4, oo = c & 15;
            const int pg = p0 + pl;
            const int y = pg / 96, x = pg - y * 96;
            const int og = o0 + oo * 8;
            const int bh = b * 8 + (og >> 6), d = og & 63;
            const size_t di = (size_t)bh * BHS_ + (size_t)y * 6144 + x * 64 + d;
            *(uint4*)(dst + di) = *(const uint4*)&smem[pl * 128 + ((oo ^ (pl & 7)) * 8)];
        }
    } else {
        // tileN[o_local][p_local], stride 136 (writes lane-contiguous)
        const int TS = 136;
        #pragma unroll
        for (int i = 0; i < 4; i++)
            #pragma unroll
            for (int r = 0; r < 4; r++) {
                const int ol_ = mrow + i * 16 + quad * 4 + r;
                const float bi = bias[o0 + ol_];
                #pragma unroll
                for (int j = 0; j < 4; j++) {
                    const int pl = ncol + j * 16 + l16;
                    smem[ol_ * TS + pl] = (bf16)(acc[i][j][r] + bi);
                }
            }
        __syncthreads();
        #pragma unroll
        for (int c = tid; c < 2048; c += 256) {
            const int ol_ = c >> 4, po = c & 15;
            const size_t di = (size_t)(b * 512 + o0 + ol_) * HW_ + p0 + po * 8;
            *(uint4*)(g + di) = *(const uint4*)&smem[ol_ * TS + po * 8];
        }
    }
}

// ---------------------------------------------------------------------------
// Kernel 2: plane transpose g -> gT, vectorized (uint2 = 4 bf16 per access).
// grid (3 strips, 2048 planes), block 256.
// ---------------------------------------------------------------------------
__global__ __launch_bounds__(256) void transpose_g(const bf16* __restrict__ src, bf16* __restrict__ dst)
{
    const int plane = blockIdx.y;
    const int y0 = blockIdx.x * 32;
    const bf16* s = src + (size_t)plane * HW_;
    bf16*       d = dst + (size_t)plane * HW_;

    __shared__ bf16 ts[32][100];   // stride 200 B: 8B-aligned, ~4-way col-read conflict
    const int tid = threadIdx.x;

    #pragma unroll
    for (int i = tid; i < 768; i += 256) {
        const int row = i / 24, seg = i % 24;
        *(uint2*)&ts[row][seg * 4] = *(const uint2*)(s + (size_t)(y0 + row) * W_ + seg * 4);
    }
    __syncthreads();
    #pragma unroll
    for (int i = tid; i < 768; i += 256) {
        const int x = i >> 3, yseg = i & 7;
        bf16 tmp[4] __attribute__((aligned(8)));
        #pragma unroll
        for (int k = 0; k < 4; k++) tmp[k] = ts[yseg * 4 + k][x];
        *(uint2*)(d + (size_t)x * H_ + y0 + yseg * 4) = *(const uint2*)tmp;
    }
}

// ---------------------------------------------------------------------------
// Kernel 3: column attention.  Block (x, bh), 512 threads / 8 waves.
// LDS 47616 B (tl+fl+el) -> 3 blocks/CU; gl staged post-QK^T into fl space.
// EXACT round-8 version.
// ---------------------------------------------------------------------------
__global__ __launch_bounds__(512) void attn_col(
    const bf16* __restrict__ tR, const bf16* __restrict__ fR, const bf16* __restrict__ gT,
    bf16* __restrict__ outC, float* __restrict__ mc, float* __restrict__ lc)
{
    const int x = blockIdx.x;
    const int bh = blockIdx.y;

    __shared__ __align__(16) bf16 tl[96][72];
    __shared__ __align__(16) bf16 fl[96][72];
    __shared__ __align__(16) bf16 el[96][104];
    // total 47616 B -> 3 blocks/CU

    const int tid = threadIdx.x;
    const size_t sbase = (size_t)bh * BHS_;

    for (int i = tid; i < 768; i += 512) {
        const int y = i >> 3, oct = i & 7;
        const size_t gi = sbase + (size_t)y * 6144 + (size_t)x * 64 + oct * 8;
        *(uint4*)&tl[y][oct * 8] = *(const uint4*)(tR + gi);
        *(uint4*)&fl[y][oct * 8] = *(const uint4*)(fR + gi);
    }
    __syncthreads();

    const int lane = tid & 63, wave = tid >> 6;
    const int l16 = lane & 15, quad = lane >> 4;

    // QK^T: 36 16x16 tiles over 8 waves
    __builtin_amdgcn_s_setprio(1);
    #pragma unroll
    for (int it = 0; it < 5; it++) {
        const int idx = wave + it * 8;
        if (idx < 36) {
            const int mt = idx / 6, nt = idx % 6;
            floatx4 a = {};
            #pragma unroll
            for (int ks = 0; ks < 2; ks++) {
                bf16x8 af = *(const bf16x8*)&tl[mt * 16 + l16][ks * 32 + quad * 8];
                bf16x8 bf_ = *(const bf16x8*)&fl[nt * 16 + l16][ks * 32 + quad * 8];
                a = __builtin_amdgcn_mfma_f32_16x16x32_bf16(af, bf_, a, 0, 0, 0);
            }
            #pragma unroll
            for (int r = 0; r < 4; r++) {
                const int row = mt * 16 + quad * 4 + r, col = nt * 16 + l16;
                el[row][col] = (row == col) ? (bf16)(-1e30f) : (bf16)a[r];
            }
        }
    }
    __builtin_amdgcn_s_setprio(0);
    __syncthreads();

    // gl staging into fl overlay (fl dead after QK^T) — overlaps softmax
    bf16 (*gl)[104] = (bf16 (*)[104])fl;   // 64*104 = 6656 <= 6912 elems
    const size_t gbase = sbase + (size_t)x * 96;   // gT[bh][d][x][*y]
    for (int i = tid; i < 768; i += 512) {
        const int d = i / 12, seg = i % 12;
        *(uint4*)&gl[d][seg * 8] = *(const uint4*)(gT + gbase + (size_t)d * HW_ + seg * 8);
    }

    // softmax: 4 threads per row, 24 vals each
    if (tid < 384) {
        const int r = tid >> 2, qu = tid & 3;
        float vals[24];
        float m = -1e30f;
        #pragma unroll
        for (int k = 0; k < 3; k++) {
            bf16x8 v8 = *(const bf16x8*)&el[r][qu * 24 + k * 8];
            #pragma unroll
            for (int e = 0; e < 8; e++) { vals[k * 8 + e] = (float)v8[e]; m = fmaxf(m, vals[k * 8 + e]); }
        }
        m = fmaxf(m, __shfl_xor(m, 1));
        m = fmaxf(m, __shfl_xor(m, 2));
        float s = 0.f;
        #pragma unroll
        for (int k = 0; k < 3; k++) {
            bf16 tmp[8] __attribute__((aligned(16)));
            #pragma unroll
            for (int e = 0; e < 8; e++) {
                const float p = __expf(vals[k * 8 + e] - m);
                s += p; tmp[e] = (bf16)p;
            }
            *(uint4*)&el[r][qu * 24 + k * 8] = *(const uint4*)tmp;
        }
        s += __shfl_xor(s, 1);
        s += __shfl_xor(s, 2);
        if (qu == 0) {
            mc[(size_t)bh * HW_ + x * 96 + r] = m;
            lc[(size_t)bh * HW_ + x * 96 + r] = s;
        }
    }
    __syncthreads();

    // PV: 24 16x16 tiles over 8 waves, out[j=y][d] into ol (overlays tl)
    bf16 (*ol)[72] = tl;
    __builtin_amdgcn_s_setprio(1);
    #pragma unroll
    for (int it = 0; it < 3; it++) {
        const int idx = wave + it * 8;
        const int mt = idx >> 2, nt = idx & 3;
        floatx4 a = {};
        #pragma unroll
        for (int ks = 0; ks < 3; ks++) {
            bf16x8 pf = *(const bf16x8*)&el[mt * 16 + l16][ks * 32 + quad * 8];
            bf16x8 gf = *(const bf16x8*)&gl[nt * 16 + l16][ks * 32 + quad * 8];
            a = __builtin_amdgcn_mfma_f32_16x16x32_bf16(pf, gf, a, 0, 0, 0);
        }
        #pragma unroll
        for (int r = 0; r < 4; r++)
            ol[mt * 16 + quad * 4 + r][nt * 16 + l16] = (bf16)a[r];
    }
    __builtin_amdgcn_s_setprio(0);
    __syncthreads();

    bf16* ob = outC + sbase + (size_t)x * 6144;
    for (int i = tid; i < 768; i += 512) {
        const int j = i >> 3, oct = i & 7;
        *(uint4*)(ob + (size_t)j * 64 + oct * 8) = *(const uint4*)&ol[j][oct * 8];
    }
}

// ---------------------------------------------------------------------------
// Kernel 4: row attention + fused merge.  Block (y, bh), 512 threads.
// r9 structure (49152 B LDS, 3 blocks/CU, T14 + setprio) + NEW coalesced
// merge-writeout: merge results staged fp32 in the dead tl footprint
// ([48][65] per half), then written out with 192-B-contiguous runs; v
// prefetched in the matching layout.  Replaces the 32B/lane stride-36KB
// scatter (50% HBM efficiency) on out-write and v-read.
// ---------------------------------------------------------------------------
__global__ __launch_bounds__(512) void attn_row_merge(
    const bf16* __restrict__ tR, const bf16* __restrict__ fR, const bf16* __restrict__ g,
    const bf16* __restrict__ outC, const float* __restrict__ mc, const float* __restrict__ lc,
    const float* __restrict__ v, const float* __restrict__ gamma, float* __restrict__ out)
{
    const int y = blockIdx.x;
    const int bh = blockIdx.y;

    __shared__ __align__(16) bf16 tl[96][72];
    __shared__ __align__(16) bf16 fl[96][72];
    __shared__ __align__(16) bf16 el[96][104];
    __shared__ float mll[96], lll[96], wrl[96], wcl[96];
    // total 49152 B -> 3 blocks/CU

    const int tid = threadIdx.x;
    const size_t sbase = (size_t)bh * BHS_;
    const size_t slice = sbase + (size_t)y * 6144;

    for (int i = tid; i < 768; i += 512) {
        const int j = i >> 3, oct = i & 7;
        *(uint4*)&tl[j][oct * 8] = *(const uint4*)(tR + slice + (size_t)j * 64 + oct * 8);
        *(uint4*)&fl[j][oct * 8] = *(const uint4*)(fR + slice + (size_t)j * 64 + oct * 8);
    }

    // --- T14 early-issue (static unroll, rule #20) -------------------------
    uint4 oc0, oc1 = {};
    {
        const int xx = tid >> 3, oct = tid & 7;            // items 0..511
        oc0 = *(const uint4*)(outC + sbase + (size_t)xx * 6144 + (size_t)y * 64 + oct * 8);
    }
    if (tid < 256) {
        const int i1 = tid + 512, xx = i1 >> 3, oct = i1 & 7;   // items 512..767
        oc1 = *(const uint4*)(outC + sbase + (size_t)xx * 6144 + (size_t)y * 64 + oct * 8);
    }
    // v prefetch in writeout layout: half h, item j -> d = j/12, xf = j%12,
    // addr = sbase + d*HW + y*96 + h*48 + xf*4   (192-B contiguous runs)
    float4 vpA, vpB = {}, vpC, vpD = {};
    {
        const int d = tid / 12, xf = tid - d * 12;
        const size_t ob = sbase + (size_t)d * HW_ + (size_t)y * 96 + xf * 4;
        vpA = *(const float4*)(v + ob);                    // h=0, s=0
        vpC = *(const float4*)(v + ob + 48);               // h=1, s=0
    }
    if (tid < 256) {
        const int j = tid + 512;
        const int d = j / 12, xf = j - d * 12;
        const size_t ob = sbase + (size_t)d * HW_ + (size_t)y * 96 + xf * 4;
        vpB = *(const float4*)(v + ob);                    // h=0, s=1
        vpD = *(const float4*)(v + ob + 48);               // h=1, s=1
    }
    float mcv = 0.f, lcv = 0.f;
    if (tid < 96) {
        mcv = mc[(size_t)bh * HW_ + tid * 96 + y];
        lcv = lc[(size_t)bh * HW_ + tid * 96 + y];
    }
    __syncthreads();

    const int lane = tid & 63, wave = tid >> 6;
    const int l16 = lane & 15, quad = lane >> 4;

    // QK^T: 36 tiles over 8 waves
    __builtin_amdgcn_s_setprio(1);
    #pragma unroll
    for (int it = 0; it < 5; it++) {
        const int idx = wave + it * 8;
        if (idx < 36) {
            const int mt = idx / 6, nt = idx % 6;
            floatx4 a = {};
            #pragma unroll
            for (int ks = 0; ks < 2; ks++) {
                bf16x8 af = *(const bf16x8*)&tl[mt * 16 + l16][ks * 32 + quad * 8];
                bf16x8 bf_ = *(const bf16x8*)&fl[nt * 16 + l16][ks * 32 + quad * 8];
                a = __builtin_amdgcn_mfma_f32_16x16x32_bf16(af, bf_, a, 0, 0, 0);
            }
            #pragma unroll
            for (int r = 0; r < 4; r++)
                el[mt * 16 + quad * 4 + r][nt * 16 + l16] = (bf16)a[r];
        }
    }
    __builtin_amdgcn_s_setprio(0);
    __syncthreads();

    // gl staging into tl overlay (tl dead after QK^T) — overlaps softmax
    bf16 (*gl)[104] = (bf16 (*)[104])tl;   // 64*104 = 6656 <= 6912 elems
    const size_t gbase = sbase + (size_t)y * 96;   // g[bh][d][y][*x]
    for (int i = tid; i < 768; i += 512) {
        const int d = i / 12, seg = i % 12;
        *(uint4*)&gl[d][seg * 8] = *(const uint4*)(g + gbase + (size_t)d * HW_ + seg * 8);
    }

    // ocl write (overlay fl; fl dead after QK^T barrier)
    bf16 (*ocl)[72] = fl;
    {
        const int xx = tid >> 3, oct = tid & 7;
        *(uint4*)&ocl[xx][oct * 8] = oc0;
    }
    if (tid < 256) {
        const int i1 = tid + 512, xx = i1 >> 3, oct = i1 & 7;
        *(uint4*)&ocl[xx][oct * 8] = oc1;
    }

    // softmax: 4 threads per row
    if (tid < 384) {
        const int r = tid >> 2, qu = tid & 3;
        float vals[24];
        float m = -1e30f;
        #pragma unroll
        for (int k = 0; k < 3; k++) {
            bf16x8 v8 = *(const bf16x8*)&el[r][qu * 24 + k * 8];
            #pragma unroll
            for (int e = 0; e < 8; e++) { vals[k * 8 + e] = (float)v8[e]; m = fmaxf(m, vals[k * 8 + e]); }
        }
        m = fmaxf(m, __shfl_xor(m, 1));
        m = fmaxf(m, __shfl_xor(m, 2));
        float s = 0.f;
        #pragma unroll
        for (int k = 0; k < 3; k++) {
            bf16 tmp[8] __attribute__((aligned(16)));
            #pragma unroll
            for (int e = 0; e < 8; e++) {
                const float p = __expf(vals[k * 8 + e] - m);
                s += p; tmp[e] = (bf16)p;
            }
            *(uint4*)&el[r][qu * 24 + k * 8] = *(const uint4*)tmp;
        }
        s += __shfl_xor(s, 1);
        s += __shfl_xor(s, 2);
        if (qu == 0) { mll[r] = m; lll[r] = s; }
    }
    __syncthreads();

    // merged-weight computation (uses prefetched mcv/lcv) + PV in registers
    if (tid < 96) {
        const float mrv = mll[tid], lrv = lll[tid];
        const float mm = fmaxf(mrv, mcv);
        const float wr = __expf(mrv - mm), wc = __expf(mcv - mm);
        const float dn = lrv * wr + lcv * wc;
        wrl[tid] = wr / dn;
        wcl[tid] = wc / dn;
    }
    floatx4 pa[3] = {};
    __builtin_amdgcn_s_setprio(1);
    #pragma unroll
    for (int it = 0; it < 3; it++) {
        const int idx = wave + it * 8;
        const int mt = idx >> 2, nt = idx & 3;
        #pragma unroll
        for (int ks = 0; ks < 3; ks++) {
            bf16x8 pf = *(const bf16x8*)&el[mt * 16 + l16][ks * 32 + quad * 8];
            bf16x8 gf = *(const bf16x8*)&gl[nt * 16 + l16][ks * 32 + quad * 8];
            pa[it] = __builtin_amdgcn_mfma_f32_16x16x32_bf16(pf, gf, pa[it], 0, 0, 0);
        }
    }
    __builtin_amdgcn_s_setprio(0);
    __syncthreads();   // all PV reads of el/gl complete (tl/gl now dead)

    // write PV results into el footprint (stride 104): el[x][d] = PV out
    #pragma unroll
    for (int it = 0; it < 3; it++) {
        const int idx = wave + it * 8;
        const int mt = idx >> 2, nt = idx & 3;
        #pragma unroll
        for (int r = 0; r < 4; r++)
            el[mt * 16 + quad * 4 + r][nt * 16 + l16] = (bf16)pa[it][r];
    }
    __syncthreads();

    // -------- coalesced merge + writeout (two halves) ----------------------
    const float gam = gamma[0];
    float* stage = (float*)&tl[0][0];   // dead region, [48][65] f32 = 12480 B

    #pragma unroll
    for (int h = 0; h < 2; h++) {
        const int xbase = h * 48;
        // (a_h) merge: items (r,d), lanes span d -> el/fl rows conflict-free
        #pragma unroll
        for (int s = 0; s < 6; s++) {
            const int j = tid + s * 512;            // < 3072
            const int r = j >> 6, d = j & 63;
            const int xx = xbase + r;
            stage[r * 65 + d] = (float)el[xx][d] * wrl[xx] + (float)ocl[xx][d] * wcl[xx];
        }
        __syncthreads();
        // (b_h) writeout: items (d, xf), 12 lanes x 16B = 192B contiguous
        {
            const int d = tid / 12, xf = tid - d * 12;
            float4 o4;
            o4.x = stage[(xf * 4 + 0) * 65 + d];
            o4.y = stage[(xf * 4 + 1) * 65 + d];
            o4.z = stage[(xf * 4 + 2) * 65 + d];
            o4.w = stage[(xf * 4 + 3) * 65 + d];
            const float4 vp = h ? vpC : vpA;
            float4 rr;
            rr.x = gam * o4.x + vp.x; rr.y = gam * o4.y + vp.y;
            rr.z = gam * o4.z + vp.z; rr.w = gam * o4.w + vp.w;
            const size_t ob = sbase + (size_t)d * HW_ + (size_t)y * 96 + xbase + xf * 4;
            *(float4*)(out + ob) = rr;
        }
        if (tid < 256) {
            const int j = tid + 512;
            const int d = j / 12, xf = j - d * 12;
            float4 o4;
            o4.x = stage[(xf * 4 + 0) * 65 + d];
            o4.y = stage[(xf * 4 + 1) * 65 + d];
            o4.z = stage[(xf * 4 + 2) * 65 + d];
            o4.w = stage[(xf * 4 + 3) * 65 + d];
            const float4 vp = h ? vpD : vpB;
            float4 rr;
            rr.x = gam * o4.x + vp.x; rr.y = gam * o4.y + vp.y;
            rr.z = gam * o4.z + vp.z; rr.w = gam * o4.w + vp.w;
            const size_t ob = sbase + (size_t)d * HW_ + (size_t)y * 96 + xbase + xf * 4;
            *(float4*)(out + ob) = rr;
        }
        __syncthreads();   // protect stage before next half overwrites
    }
}

// ---------------------------------------------------------------------------
extern "C" void kernel_launch(void* const* d_in, const int* in_sizes, int n_in,
                              void* d_out, int out_size, void* d_ws, size_t ws_size,
                              hipStream_t stream)
{
    const float* q     = (const float*)d_in[0];
    const float* v     = (const float*)d_in[1];
    const float* Wq    = (const float*)d_in[2];
    const float* bq    = (const float*)d_in[3];
    const float* Wk    = (const float*)d_in[4];
    const float* bk    = (const float*)d_in[5];
    const float* Wv    = (const float*)d_in[6];
    const float* bv    = (const float*)d_in[7];
    const float* gamma = (const float*)d_in[8];
    float* out = (float*)d_out;

    char* w = (char*)d_ws;
    const size_t Tb = T_ELEMS * sizeof(bf16);   // 37,748,736 B per slot
    bf16* qbT  = (bf16*)(w + 0 * Tb);   // dead after conv -> reused by outC
    bf16* vbT  = (bf16*)(w + 1 * Tb);   // dead after conv -> reused by gT
    bf16* tR   = (bf16*)(w + 2 * Tb);
    bf16* fR   = (bf16*)(w + 3 * Tb);
    bf16* g    = (bf16*)(w + 4 * Tb);
    bf16* gT   = (bf16*)(w + 1 * Tb);
    bf16* outC = (bf16*)(w + 0 * Tb);
    bf16* Wb   = (bf16*)(w + 6 * Tb);                       // 1.57 MB
    float* mc  = (float*)(w + 6 * Tb + 1572864);
    float* lc  = mc + S_ELEMS;
    // high-water: 6*Tb + 1.57 MB + 2.36 MB = 230.4 MB

    cast_qv <<<dim3(144, 8, 9), 256, 0, stream>>>(q, v, Wq, Wk, Wv, qbT, vbT, Wb);
    conv_mfma<<<dim3(72, 4, 12), 256, 0, stream>>>(Wb, bq, bk, bv, qbT, vbT, tR, fR, g);
    transpose_g<<<dim3(3, 2048), 256, 0, stream>>>(g, gT);
    attn_col<<<dim3(96, BH_), 512, 0, stream>>>(tR, fR, gT, outC, mc, lc);
    attn_row_merge<<<dim3(96, BH_), 512, 0, stream>>>(tR, fR, g, outC, mc, lc, v, gamma, out);
}